// Round 1
// 576.522 us; speedup vs baseline: 1.1307x; 1.1307x over previous
//
#include <hip/hip_runtime.h>

#define DEG 16
#define DD  128
#define KT  10      // template nodes
#define TT  10      // templates
#define MM  17      // m = DEG+1
#define NPB 4       // nodes per block
#define THREADS 640 // 10 waves: wave w <-> template w

#if __has_builtin(__builtin_amdgcn_exp2f)
#define FEXP2(x) __builtin_amdgcn_exp2f(x)
#else
#define FEXP2(x) exp2f(x)
#endif

#if __has_builtin(__builtin_amdgcn_rcpf)
#define FRCP(x) __builtin_amdgcn_rcpf(x)
#else
#define FRCP(x) (1.0f / (x))
#endif

#if __has_builtin(__builtin_amdgcn_logf)
#define FLOG2(x) __builtin_amdgcn_logf(x)
#else
#define FLOG2(x) __log2f(x)
#endif

// (1/EPS) * log2(e) with EPS = 0.5
#define TWO_LOG2E 2.8853900817779268f
// log2(e)  ( = TWO_LOG2E * 0.5 : scale for the hoisted exp2 of 0.5*Mc )
#define NLOG2E    1.4426950408889634f
// EPS*ln2  ( = 1/TWO_LOG2E : recovers 0.5*Mc from log2(eM) )
#define EPSLN2    0.34657359027997264f

typedef float v2f __attribute__((ext_vector_type(2)));
typedef float v4f __attribute__((ext_vector_type(4)));

// ---- packed fp32 fma: 2 floats per instruction, full VALU rate on CDNA2+ ----
__device__ __forceinline__ v2f pk_fma(v2f a, v2f b, v2f c) {
    asm("v_pk_fma_f32 %0, %1, %2, %0" : "+v"(c) : "v"(a), "v"(b));
    return c;
}

// ---- legacy builtin-based 16-lane sum (used once for the final obj) ----
template <int CTRL>
__device__ __forceinline__ float dpp_add(float x) {
    union { float f; int i; } a, b;
    a.f = x;
    b.i = __builtin_amdgcn_update_dpp(0, a.i, CTRL, 0xF, 0xF, true);
    return x + b.f;
}
__device__ __forceinline__ float sum16(float t) {
    t = dpp_add<0xB1>(t);   // quad_perm [1,0,3,2]  == xor 1
    t = dpp_add<0x4E>(t);   // quad_perm [2,3,0,1]  == xor 2
    t = dpp_add<0x124>(t);  // row_ror:4
    t = dpp_add<0x128>(t);  // row_ror:8
    return t;
}

// ---- hand-fused multi-value 16-lane reductions: guaranteed v_add_f32_dpp ----
// Hazard: "VALU writes VGPR -> DPP reads it" needs 2 wait states. Entry is
// guarded by s_nop 1; inside the block, stage s+1 of value i is >=4
// instructions after stage s of value i (chunk width 5/6), so no nops needed.
#define _D(i, CTRL) "v_add_f32_dpp %" #i ", %" #i ", %" #i " " CTRL \
                    " row_mask:0xf bank_mask:0xf bound_ctrl:0\n\t"
#define _C1 "quad_perm:[1,0,3,2]"
#define _C2 "quad_perm:[2,3,0,1]"
#define _C3 "row_ror:4"
#define _C4 "row_ror:8"

__device__ __forceinline__ void sum16x6(float& a0, float& a1, float& a2,
                                        float& a3, float& a4, float& a5) {
    asm("s_nop 1\n\t"
        _D(0,_C1) _D(1,_C1) _D(2,_C1) _D(3,_C1) _D(4,_C1) _D(5,_C1)
        _D(0,_C2) _D(1,_C2) _D(2,_C2) _D(3,_C2) _D(4,_C2) _D(5,_C2)
        _D(0,_C3) _D(1,_C3) _D(2,_C3) _D(3,_C3) _D(4,_C3) _D(5,_C3)
        _D(0,_C4) _D(1,_C4) _D(2,_C4) _D(3,_C4) _D(4,_C4) _D(5,_C4)
        : "+v"(a0), "+v"(a1), "+v"(a2), "+v"(a3), "+v"(a4), "+v"(a5));
}

__device__ __forceinline__ void sum16x5(float& a0, float& a1, float& a2,
                                        float& a3, float& a4) {
    asm("s_nop 1\n\t"
        _D(0,_C1) _D(1,_C1) _D(2,_C1) _D(3,_C1) _D(4,_C1)
        _D(0,_C2) _D(1,_C2) _D(2,_C2) _D(3,_C2) _D(4,_C2)
        _D(0,_C3) _D(1,_C3) _D(2,_C3) _D(3,_C3) _D(4,_C3)
        _D(0,_C4) _D(1,_C4) _D(2,_C4) _D(3,_C4) _D(4,_C4)
        : "+v"(a0), "+v"(a1), "+v"(a2), "+v"(a3), "+v"(a4));
}

// One Sinkhorn row-chunk: t_j = sum16(eK_j * v); u1_j = 1/t_j; colacc += eK_j*u1_j.
// colacc accumulation order matches the original serial j-order exactly.
#define SINK6(J) do {                                                         \
    float b0 = eK[J+0]*v, b1 = eK[J+1]*v, b2 = eK[J+2]*v,                     \
          b3 = eK[J+3]*v, b4 = eK[J+4]*v, b5 = eK[J+5]*v;                     \
    sum16x6(b0,b1,b2,b3,b4,b5);                                               \
    u1[J+0]=FRCP(b0); u1[J+1]=FRCP(b1); u1[J+2]=FRCP(b2);                     \
    u1[J+3]=FRCP(b3); u1[J+4]=FRCP(b4); u1[J+5]=FRCP(b5);                     \
    colacc = fmaf(eK[J+0],u1[J+0],colacc);                                    \
    colacc = fmaf(eK[J+1],u1[J+1],colacc);                                    \
    colacc = fmaf(eK[J+2],u1[J+2],colacc);                                    \
    colacc = fmaf(eK[J+3],u1[J+3],colacc);                                    \
    colacc = fmaf(eK[J+4],u1[J+4],colacc);                                    \
    colacc = fmaf(eK[J+5],u1[J+5],colacc);                                    \
} while (0)

#define SINK5(J) do {                                                         \
    float b0 = eK[J+0]*v, b1 = eK[J+1]*v, b2 = eK[J+2]*v,                     \
          b3 = eK[J+3]*v, b4 = eK[J+4]*v;                                     \
    sum16x5(b0,b1,b2,b3,b4);                                                  \
    u1[J+0]=FRCP(b0); u1[J+1]=FRCP(b1); u1[J+2]=FRCP(b2);                     \
    u1[J+3]=FRCP(b3); u1[J+4]=FRCP(b4);                                       \
    colacc = fmaf(eK[J+0],u1[J+0],colacc);                                    \
    colacc = fmaf(eK[J+1],u1[J+1],colacc);                                    \
    colacc = fmaf(eK[J+2],u1[J+2],colacc);                                    \
    colacc = fmaf(eK[J+3],u1[J+3],colacc);                                    \
    colacc = fmaf(eK[J+4],u1[J+4],colacc);                                    \
} while (0)

__global__ __launch_bounds__(THREADS) void ltfgw_kernel(
    const float* __restrict__ x,      // [N,128]
    const int*   __restrict__ ei,     // edge_index[0], [N*DEG]
    const float* __restrict__ tmpl,   // [T,K,K]
    const float* __restrict__ tf,     // [T,K,128]
    float* __restrict__ out,          // [N,T]
    int N)
{
    constexpr int SLAB = MM * DD + 4;   // +4 floats: node slabs land on disjoint banks
    __shared__ float sFi[NPB * SLAB];
    __shared__ float sNrm[NPB][MM];

    const int tid = threadIdx.x;
    const int b0  = blockIdx.x * NPB;

    // ---- stage Fi: 68 rows of 128 floats, 32 lanes of float4 per row
    {
        const int kq = tid & 31;
        for (int r = tid >> 5; r < NPB * MM; r += (THREADS >> 5)) {
            int p = r / MM, j = r % MM;
            int node = b0 + p;
            if (node < N) {
                int src = (j == 0) ? node : ei[node * DEG + (j - 1)];
                float4 v = *(const float4*)(x + (size_t)src * DD + kq * 4);
                *(float4*)(&sFi[p * SLAB + j * DD + kq * 4]) = v;
            }
        }
    }
    __syncthreads();

    // ---- per-row squared norms
    if (tid < NPB * MM) {
        int p = tid / MM, j = tid % MM;
        const float* row = &sFi[p * SLAB + j * DD];
        float acc = 0.f;
        for (int kidx = 0; kidx < 32; ++kidx) {
            int kq2 = (kidx + tid) & 31;
            float4 v = *(const float4*)(row + kq2 * 4);
            acc += v.x * v.x + v.y * v.y + v.z * v.z + v.w * v.w;
        }
        sNrm[p][j] = acc;
    }
    __syncthreads();

    const int w    = tid >> 6;         // template index
    const int lane = tid & 63;
    const int p    = lane >> 4;        // node sub-slot 0..3
    const int c    = lane & 15;        // template column (active if <10)
    const bool act = (c < KT);
    const int node = b0 + p;
    const int cc   = act ? c : 0;

    // ---- Ct row + ct2q = (Ct^2 @ q)[c]
    float CtRow[KT];
    float ct2q = 0.f;
#pragma unroll
    for (int jj = 0; jj < KT; ++jj) {
        CtRow[jj] = tmpl[(w * KT + cc) * KT + jj];
        ct2q += CtRow[jj] * CtRow[jj];
    }
    ct2q *= (1.f / KT);

    // ---- dots via packed fp32 fma: dot2[j] holds {even,odd}-pair partial sums
    v2f dot2[MM];
#pragma unroll
    for (int j = 0; j < MM; ++j) dot2[j] = (v2f){0.f, 0.f};
    v2f nft2 = (v2f){0.f, 0.f};
    const float* ftrow = tf + (size_t)(w * KT + cc) * DD;
    for (int kk = 0; kk < DD; kk += 4) {
        v4f f4 = *(const v4f*)(ftrow + kk);
        v2f flo = f4.lo, fhi = f4.hi;
        nft2 = pk_fma(flo, flo, nft2);
        nft2 = pk_fma(fhi, fhi, nft2);
#pragma unroll
        for (int j = 0; j < MM; ++j) {
            v4f a4 = *(const v4f*)(&sFi[p * SLAB + j * DD + kk]);
            dot2[j] = pk_fma(a4.lo, flo, dot2[j]);
            dot2[j] = pk_fma(a4.hi, fhi, dot2[j]);
        }
    }
    float nft = nft2.x + nft2.y;

    // ---- hoisted mirror factor: eM[j] = exp2(-log2e * Mc[j])  (outer-invariant)
    // Mc is not kept; epilogue recovers 0.5*Mc = -EPSLN2*log2(eM).
    float eM[MM];
#pragma unroll
    for (int j = 0; j < MM; ++j) {
        float mc = (sNrm[p][j] + nft - 2.f * (dot2[j].x + dot2[j].y)) * (1.f / DD);
        eM[j] = act ? FEXP2(-NLOG2E * mc) : 1.f;
    }

    // ---- scaled-domain proximal Sinkhorn (pw folded out of the u-update)
    const float pw = 1.f / MM;
    const float QP = 17.f / 10.f;      // qw / pw
    const int gbase = lane & ~15;

    float Tp[MM], eK[MM], u1[MM];
#pragma unroll
    for (int j = 0; j < MM; ++j) Tp[j] = act ? (1.f / (MM * KT)) : 0.f;

    float obj = 0.f;

#pragma unroll 1
    for (int outer = 0; outer < 5; ++outer) {
        float colsum = 0.f;
#pragma unroll
        for (int j = 0; j < MM; ++j) colsum += Tp[j];
        float t0v = Tp[0];
        float s   = colsum - t0v;

        // (Ci@Tp@Ct^T): row0 -> Ct . s ; rows>=1 -> Ct . Tp[0,:]
        float Cs = 0.f, C0 = 0.f;
#pragma unroll
        for (int jj = 0; jj < KT; ++jj) {
            float sv = __shfl(s,   gbase + jj, 64);
            float tv = __shfl(t0v, gbase + jj, 64);
            Cs += CtRow[jj] * sv;
            C0 += CtRow[jj] * tv;
        }

        // mirror step: eK = Tp * eM * exp2(-TWO_LOG2E * gw); gw has only 2 values
        float E0 = FEXP2(-TWO_LOG2E * ((16.f / 17.f) + ct2q - 2.f * Cs));
        float E1 = FEXP2(-TWO_LOG2E * ((1.f  / 17.f) + ct2q - 2.f * C0));
#pragma unroll
        for (int j = 0; j < MM; ++j)
            eK[j] = Tp[j] * (eM[j] * ((j == 0) ? E0 : E1));   // inactive: Tp==0

        // 10 Sinkhorn iterations; u1 = 1/(K v), v = (qw/pw)/(K^T u1)
        float v = 1.f;
#pragma unroll 1
        for (int it = 0; it < 10; ++it) {
            float colacc = 0.f;
            SINK6(0);
            SINK6(6);
            SINK5(12);
            v = act ? QP * FRCP(colacc) : 0.f;
        }

        float pv = pw * v;
#pragma unroll
        for (int j = 0; j < MM; ++j) Tp[j] = eK[j] * u1[j] * pv;
    }

    // ---- final objective (the old outer==5 path, hoisted out of the loop)
    {
        float colsum = 0.f;
#pragma unroll
        for (int j = 0; j < MM; ++j) colsum += Tp[j];
        float t0v = Tp[0];
        float s   = colsum - t0v;
        float Cs = 0.f, C0 = 0.f;
#pragma unroll
        for (int jj = 0; jj < KT; ++jj) {
            float sv = __shfl(s,   gbase + jj, 64);
            float tv = __shfl(t0v, gbase + jj, 64);
            Cs += CtRow[jj] * sv;
            C0 += CtRow[jj] * tv;
        }
#pragma unroll
        for (int j = 0; j < MM; ++j) {
            float gw = ((j == 0) ? (16.f / 17.f) : (1.f / 17.f)) + ct2q
                       - 2.f * ((j == 0) ? Cs : C0);
            float halfM = -EPSLN2 * FLOG2(eM[j]);   // == 0.5*Mc[j]
            obj += Tp[j] * (halfM + 0.5f * gw);
        }
    }

    // sum over the 16-lane group (inactive lanes contribute exact 0)
    obj = sum16(obj);

    if (act && c == 0 && node < N) out[node * TT + w] = obj;
}

extern "C" void kernel_launch(void* const* d_in, const int* in_sizes, int n_in,
                              void* d_out, int out_size, void* d_ws, size_t ws_size,
                              hipStream_t stream) {
    const float* x    = (const float*)d_in[0];
    const int*   ei   = (const int*)d_in[1];
    const float* tmpl = (const float*)d_in[2];
    const float* tf   = (const float*)d_in[3];
    float* out = (float*)d_out;
    int N = in_sizes[0] / DD;
    int grid = (N + NPB - 1) / NPB;
    hipLaunchKernelGGL(ltfgw_kernel, dim3(grid), dim3(THREADS), 0, stream,
                       x, ei, tmpl, tf, out, N);
}

// Round 2
// 566.995 us; speedup vs baseline: 1.1497x; 1.0168x over previous
//
#include <hip/hip_runtime.h>

#define DEG 16
#define DD  128
#define KT  10      // template nodes (K)
#define TT  10      // templates
#define MM  17      // m = DEG+1
#define NPB 4       // nodes per block
#define THREADS 640 // 10 waves: wave w <-> template w
#define PITCH 132   // Fi row pitch in floats: 128+4 staggers banks for row-strided reads

#if __has_builtin(__builtin_amdgcn_exp2f)
#define FEXP2(x) __builtin_amdgcn_exp2f(x)
#else
#define FEXP2(x) exp2f(x)
#endif

#if __has_builtin(__builtin_amdgcn_rcpf)
#define FRCP(x) __builtin_amdgcn_rcpf(x)
#else
#define FRCP(x) (1.0f / (x))
#endif

#if __has_builtin(__builtin_amdgcn_logf)
#define FLOG2(x) __builtin_amdgcn_logf(x)
#else
#define FLOG2(x) __log2f(x)
#endif

// (1/EPS) * log2(e) with EPS = 0.5
#define TWO_LOG2E 2.8853900817779268f
// log2(e): scale for the hoisted exp2 of 0.5*Mc
#define NLOG2E    1.4426950408889634f
// EPS*ln2 = 1/TWO_LOG2E: recovers 0.5*Mc from log2(eM)
#define EPSLN2    0.34657359027997264f

typedef float v2f __attribute__((ext_vector_type(2)));
typedef float v4f __attribute__((ext_vector_type(4)));

// ---- packed fp32 fma: 2 floats per instruction, full VALU rate ----
__device__ __forceinline__ v2f pk_fma(v2f a, v2f b, v2f c) {
    asm("v_pk_fma_f32 %0, %1, %2, %0" : "+v"(c) : "v"(a), "v"(b));
    return c;
}

// ---- builtin-based 16-lane sum (compiler handles hazards) for the final obj ----
template <int CTRL>
__device__ __forceinline__ float dpp_add(float x) {
    union { float f; int i; } a, b;
    a.f = x;
    b.i = __builtin_amdgcn_update_dpp(0, a.i, CTRL, 0xF, 0xF, true);
    return x + b.f;
}
__device__ __forceinline__ float sum16(float t) {
    t = dpp_add<0xB1>(t);   // quad_perm [1,0,3,2]  == xor 1
    t = dpp_add<0x4E>(t);   // quad_perm [2,3,0,1]  == xor 2
    t = dpp_add<0x124>(t);  // row_ror:4
    t = dpp_add<0x128>(t);  // row_ror:8
    return t;
}

// ---- hand-fused multi-value 16-lane reductions: guaranteed v_add_f32_dpp ----
// Hazard: "VALU writes VGPR -> DPP reads it" needs 2 wait states. Entry guarded
// by s_nop 1; within a block, stage s+1 of value i is >=4 (x5) instructions
// after stage s of value i, so no interior nops needed.
#define _D(i, CTRL) "v_add_f32_dpp %" #i ", %" #i ", %" #i " " CTRL \
                    " row_mask:0xf bank_mask:0xf bound_ctrl:0\n\t"
#define _C1 "quad_perm:[1,0,3,2]"
#define _C2 "quad_perm:[2,3,0,1]"
#define _C3 "row_ror:4"
#define _C4 "row_ror:8"

__device__ __forceinline__ void sum16x6(float& a0, float& a1, float& a2,
                                        float& a3, float& a4, float& a5) {
    asm("s_nop 1\n\t"
        _D(0,_C1) _D(1,_C1) _D(2,_C1) _D(3,_C1) _D(4,_C1) _D(5,_C1)
        _D(0,_C2) _D(1,_C2) _D(2,_C2) _D(3,_C2) _D(4,_C2) _D(5,_C2)
        _D(0,_C3) _D(1,_C3) _D(2,_C3) _D(3,_C3) _D(4,_C3) _D(5,_C3)
        _D(0,_C4) _D(1,_C4) _D(2,_C4) _D(3,_C4) _D(4,_C4) _D(5,_C4)
        : "+v"(a0), "+v"(a1), "+v"(a2), "+v"(a3), "+v"(a4), "+v"(a5));
}

__device__ __forceinline__ void sum16x5(float& a0, float& a1, float& a2,
                                        float& a3, float& a4) {
    asm("s_nop 1\n\t"
        _D(0,_C1) _D(1,_C1) _D(2,_C1) _D(3,_C1) _D(4,_C1)
        _D(0,_C2) _D(1,_C2) _D(2,_C2) _D(3,_C2) _D(4,_C2)
        _D(0,_C3) _D(1,_C3) _D(2,_C3) _D(3,_C3) _D(4,_C3)
        _D(0,_C4) _D(1,_C4) _D(2,_C4) _D(3,_C4) _D(4,_C4)
        : "+v"(a0), "+v"(a1), "+v"(a2), "+v"(a3), "+v"(a4));
}

// TRANSPOSED LAYOUT:
//   wave w <-> template w; 64 lanes = 4 groups (node sub-slot p) x 16 lanes.
//   Lane l in a group owns ROW j = l+1 (the 16 neighbors fit exactly);
//   the center row j=0 is register-replicated across the group.
//   K=10 template columns live in registers (arrays [KT]).
//   Row-sums over K: in-register dots (2 rcp/iter). Column-sums over the 16
//   neighbor rows: 16-lane DPP butterflies (40 DPP/iter), + replicated j0 term.
__global__ __launch_bounds__(THREADS) void ltfgw_kernel(
    const float* __restrict__ x,      // [N,128]
    const int*   __restrict__ ei,     // edge_index[0], [N*DEG]
    const float* __restrict__ tmpl,   // [T,K,K]
    const float* __restrict__ tf,     // [T,K,128]
    float* __restrict__ out,          // [N,T]
    int N)
{
    constexpr int SLAB = MM * PITCH;     // 2244 floats per node
    __shared__ float sFi[NPB * SLAB];    // 35904 B

    const int tid = threadIdx.x;
    const int b0  = blockIdx.x * NPB;

    // ---- stage Fi: 68 rows of 128 floats at pitch 132, 32 lanes of float4/row
    {
        const int kq = tid & 31;
        for (int r = tid >> 5; r < NPB * MM; r += (THREADS >> 5)) {
            int p = r / MM, j = r % MM;
            int node = b0 + p;
            if (node < N) {
                int src = (j == 0) ? node : ei[node * DEG + (j - 1)];
                float4 v4 = *(const float4*)(x + (size_t)src * DD + kq * 4);
                *(float4*)(&sFi[p * SLAB + j * PITCH + kq * 4]) = v4;
            }
        }
    }
    __syncthreads();

    const int w     = tid >> 6;                       // template index
    const int wu    = __builtin_amdgcn_readfirstlane(w);
    const int lane  = tid & 63;
    const int p     = lane >> 4;                      // node sub-slot 0..3
    const int l     = lane & 15;                      // own row j = l+1
    const int gbase = lane & ~15;
    const int node  = b0 + p;

    // ---- Ct row for column l (lanes l<10 meaningful; l>=10 clamped, never broadcast)
    const int cl = (l < KT) ? l : 0;
    float CtRow[KT];
    float ct2q = 0.f;
#pragma unroll
    for (int jj = 0; jj < KT; ++jj) {
        CtRow[jj] = tmpl[(wu * KT + cl) * KT + jj];
        ct2q += CtRow[jj] * CtRow[jj];
    }
    ct2q *= (1.f / KT);

    // ---- M main pass: own row (j=l+1) vs all 10 template rows.
    // Own-row reads: ds_read_b128 at pitch 132 -> 2-way bank alias (free).
    // Template reads: wave-uniform address -> scalar-cache broadcast.
    const float* myrow = &sFi[p * SLAB + (l + 1) * PITCH];
    const float* tw    = tf + (size_t)wu * KT * DD;
    v2f dotv[KT];
#pragma unroll
    for (int c = 0; c < KT; ++c) dotv[c] = (v2f){0.f, 0.f};
    v2f nrmv = (v2f){0.f, 0.f};
    for (int kk = 0; kk < DD; kk += 4) {
        v4f a4 = *(const v4f*)(myrow + kk);
        v2f alo = a4.lo, ahi = a4.hi;
        nrmv = pk_fma(alo, alo, nrmv);
        nrmv = pk_fma(ahi, ahi, nrmv);
#pragma unroll
        for (int c = 0; c < KT; ++c) {
            v4f f4 = *(const v4f*)(tw + c * DD + kk);
            dotv[c] = pk_fma(alo, f4.lo, dotv[c]);
            dotv[c] = pk_fma(ahi, f4.hi, dotv[c]);
        }
    }
    float nrm_own = nrmv.x + nrmv.y;
    float dot_own[KT];
#pragma unroll
    for (int c = 0; c < KT; ++c) dot_own[c] = dotv[c].x + dotv[c].y;

    // ---- mini-pass: center row j=0 dots + template norms + row0 norm,
    // k-distributed: lane l covers k in [8l, 8l+8), then 16-lane reduce.
    float dot0[KT], nft[KT], n0p;
    {
        const float* row0 = &sFi[p * SLAB + 8 * l];
        v4f z0 = *(const v4f*)(row0);
        v4f z1 = *(const v4f*)(row0 + 4);
        v2f nn = pk_fma(z0.lo, z0.lo, (v2f){0.f, 0.f});
        nn = pk_fma(z0.hi, z0.hi, nn);
        nn = pk_fma(z1.lo, z1.lo, nn);
        nn = pk_fma(z1.hi, z1.hi, nn);
        n0p = nn.x + nn.y;
#pragma unroll
        for (int c = 0; c < KT; ++c) {
            const float* tr = tw + c * DD + 8 * l;   // coalesced across lanes
            v4f t0_ = *(const v4f*)(tr);
            v4f t1_ = *(const v4f*)(tr + 4);
            v2f d = pk_fma(z0.lo, t0_.lo, (v2f){0.f, 0.f});
            d = pk_fma(z0.hi, t0_.hi, d);
            d = pk_fma(z1.lo, t1_.lo, d);
            d = pk_fma(z1.hi, t1_.hi, d);
            dot0[c] = d.x + d.y;
            v2f nf = pk_fma(t0_.lo, t0_.lo, (v2f){0.f, 0.f});
            nf = pk_fma(t0_.hi, t0_.hi, nf);
            nf = pk_fma(t1_.lo, t1_.lo, nf);
            nf = pk_fma(t1_.hi, t1_.hi, nf);
            nft[c] = nf.x + nf.y;
        }
        sum16x6(dot0[0], dot0[1], dot0[2], dot0[3], dot0[4], dot0[5]);
        sum16x5(dot0[6], dot0[7], dot0[8], dot0[9], n0p);
        sum16x5(nft[0], nft[1], nft[2], nft[3], nft[4]);
        sum16x5(nft[5], nft[6], nft[7], nft[8], nft[9]);
    }

    // ---- hoisted mirror factors eM = exp2(-log2e * Mc) (outer-invariant)
    float eM_own[KT], eM0[KT];
#pragma unroll
    for (int c = 0; c < KT; ++c) {
        float mc0 = (n0p + nft[c] - 2.f * dot0[c]) * (1.f / DD);
        eM0[c] = FEXP2(-NLOG2E * mc0);
        float mcw = (nrm_own + nft[c] - 2.f * dot_own[c]) * (1.f / DD);
        eM_own[c] = FEXP2(-NLOG2E * mcw);
    }

    // ---- scaled-domain proximal Sinkhorn, transposed
    const float pw = 1.f / MM;
    const float QP = 17.f / 10.f;      // qw / pw

    float Tp_own[KT], Tp0[KT], eK_own[KT], eK0[KT], vv[KT];
#pragma unroll
    for (int c = 0; c < KT; ++c) {
        Tp_own[c] = 1.f / (MM * KT);
        Tp0[c]    = 1.f / (MM * KT);
    }
    float u_own = 0.f, u0 = 0.f;

#pragma unroll 1
    for (int outer = 0; outer < 5; ++outer) {
        // s[c] = sum over neighbor rows (the 16 lanes) of Tp; t0 row is Tp0 (in-reg)
        float s[KT];
#pragma unroll
        for (int c = 0; c < KT; ++c) s[c] = Tp_own[c];
        sum16x5(s[0], s[1], s[2], s[3], s[4]);
        sum16x5(s[5], s[6], s[7], s[8], s[9]);

        // distributed Cs/C0 on lanes l<10 (column l), then E broadcast
        float Cs = 0.f, C0 = 0.f;
#pragma unroll
        for (int jj = 0; jj < KT; ++jj) {
            Cs = fmaf(CtRow[jj], s[jj],   Cs);
            C0 = fmaf(CtRow[jj], Tp0[jj], C0);
        }
        float e0 = FEXP2(-TWO_LOG2E * ((16.f / 17.f) + ct2q - 2.f * Cs));
        float e1 = FEXP2(-TWO_LOG2E * ((1.f  / 17.f) + ct2q - 2.f * C0));

#pragma unroll
        for (int c = 0; c < KT; ++c) {
            float E1c = __shfl(e1, gbase + c, 64);
            eK_own[c] = Tp_own[c] * (eM_own[c] * E1c);
            float E0c = __shfl(e0, gbase + c, 64);
            eK0[c]    = Tp0[c]    * (eM0[c]   * E0c);
            vv[c] = 1.f;
        }

        // 10 Sinkhorn iterations: u = 1/(K v) (in-register dot, 2 rcp);
        // colacc over 17 rows = 16-lane butterfly + replicated j0 term.
#pragma unroll 1
        for (int it = 0; it < 10; ++it) {
            float ra = eK_own[0] * vv[0], rb = eK_own[1] * vv[1];
            float qa = eK0[0]   * vv[0], qb = eK0[1]   * vv[1];
#pragma unroll
            for (int c = 2; c < KT; c += 2) {
                ra = fmaf(eK_own[c],     vv[c],     ra);
                rb = fmaf(eK_own[c + 1], vv[c + 1], rb);
                qa = fmaf(eK0[c],        vv[c],     qa);
                qb = fmaf(eK0[c + 1],    vv[c + 1], qb);
            }
            u_own = FRCP(ra + rb);
            u0    = FRCP(qa + qb);
            float t[KT];
#pragma unroll
            for (int c = 0; c < KT; ++c) t[c] = eK_own[c] * u_own;
            sum16x5(t[0], t[1], t[2], t[3], t[4]);
            sum16x5(t[5], t[6], t[7], t[8], t[9]);
#pragma unroll
            for (int c = 0; c < KT; ++c) {
                float cc2 = fmaf(eK0[c], u0, t[c]);
                vv[c] = QP * FRCP(cc2);
            }
        }

        float puw = pw * u_own, pu0 = pw * u0;
#pragma unroll
        for (int c = 0; c < KT; ++c) {
            Tp_own[c] = (eK_own[c] * puw) * vv[c];
            Tp0[c]    = (eK0[c]   * pu0) * vv[c];
        }
    }

    // ---- final objective from converged Tp (6th Cs/C0 evaluation)
    float obj;
    {
        float s[KT];
#pragma unroll
        for (int c = 0; c < KT; ++c) s[c] = Tp_own[c];
        sum16x5(s[0], s[1], s[2], s[3], s[4]);
        sum16x5(s[5], s[6], s[7], s[8], s[9]);
        float Cs = 0.f, C0 = 0.f;
#pragma unroll
        for (int jj = 0; jj < KT; ++jj) {
            Cs = fmaf(CtRow[jj], s[jj],   Cs);
            C0 = fmaf(CtRow[jj], Tp0[jj], C0);
        }
        float g0l = (16.f / 17.f) + ct2q - 2.f * Cs;   // gw for row 0, column l
        float g1l = (1.f  / 17.f) + ct2q - 2.f * C0;   // gw for rows>=1, column l
        float obj_own = 0.f, obj0 = 0.f;
#pragma unroll
        for (int c = 0; c < KT; ++c) {
            float G1c = __shfl(g1l, gbase + c, 64);
            float hM  = -EPSLN2 * FLOG2(eM_own[c]);    // == 0.5*Mc_own[c]
            obj_own += Tp_own[c] * (hM + 0.5f * G1c);
            float G0c = __shfl(g0l, gbase + c, 64);
            float hM0 = -EPSLN2 * FLOG2(eM0[c]);       // == 0.5*Mc0[c]
            obj0 += Tp0[c] * (hM0 + 0.5f * G0c);
        }
        obj = sum16(obj_own) + obj0;   // obj0 identical on all 16 lanes; add once
    }

    if (l == 0 && node < N) out[node * TT + w] = obj;
}

extern "C" void kernel_launch(void* const* d_in, const int* in_sizes, int n_in,
                              void* d_out, int out_size, void* d_ws, size_t ws_size,
                              hipStream_t stream) {
    const float* x    = (const float*)d_in[0];
    const int*   ei   = (const int*)d_in[1];
    const float* tmpl = (const float*)d_in[2];
    const float* tf   = (const float*)d_in[3];
    float* out = (float*)d_out;
    int N = in_sizes[0] / DD;
    int grid = (N + NPB - 1) / NPB;
    hipLaunchKernelGGL(ltfgw_kernel, dim3(grid), dim3(THREADS), 0, stream,
                       x, ei, tmpl, tf, out, N);
}

// Round 3
// 426.875 us; speedup vs baseline: 1.5271x; 1.3282x over previous
//
#include <hip/hip_runtime.h>

#define DEG 16
#define DD  128
#define KT  10      // template nodes (K)
#define TT  10      // templates
#define MM  17      // m = DEG+1
#define NPB 4       // nodes per block
#define THREADS 640 // 10 waves: wave w <-> template w
#define PITCH 132   // Fi row pitch in floats

#if __has_builtin(__builtin_amdgcn_exp2f)
#define FEXP2(x) __builtin_amdgcn_exp2f(x)
#else
#define FEXP2(x) exp2f(x)
#endif

#if __has_builtin(__builtin_amdgcn_rcpf)
#define FRCP(x) __builtin_amdgcn_rcpf(x)
#else
#define FRCP(x) (1.0f / (x))
#endif

#if __has_builtin(__builtin_amdgcn_logf)
#define FLOG2(x) __builtin_amdgcn_logf(x)
#else
#define FLOG2(x) __log2f(x)
#endif

// (1/EPS)*log2(e), EPS = 0.5
#define TWO_LOG2E 2.8853900817779268f
// log2(e): scale for the hoisted exp2 of 0.5*Mc
#define NLOG2E    1.4426950408889634f
// EPS*ln2 = 1/TWO_LOG2E: recovers 0.5*Mc from log2(eM)
#define EPSLN2    0.34657359027997264f
// QP = qw/pw = 17/10 moved into the 2-wide u-update: RQP = 1/QP = 10/17
#define RQP       0.5882352941176471f
// vv'' initial value = 1/QP
#define VV0       0.5882352941176471f
// pw*QP = (1/17)*(17/10) = 1/10 exactly
#define PWQP      0.1f

typedef float v2f __attribute__((ext_vector_type(2)));
typedef float v4f __attribute__((ext_vector_type(4)));

// packed fp32 fma, both mul operands in VGPRs
__device__ __forceinline__ v2f pk_fma(v2f a, v2f b, v2f c) {
    asm("v_pk_fma_f32 %0, %1, %2, %0" : "+v"(c) : "v"(a), "v"(b));
    return c;
}
// packed fp32 fma with a wave-uniform operand pinned to an SGPR pair:
// no v_mov copies, template data stays in scalar registers.
__device__ __forceinline__ v2f pk_fma_s(v2f a, v2f bs, v2f c) {
    asm("v_pk_fma_f32 %0, %1, %2, %0" : "+v"(c) : "v"(a), "s"(bs));
    return c;
}

// builtin-based 16-lane sum for the final objective
template <int CTRL>
__device__ __forceinline__ float dpp_add(float x) {
    union { float f; int i; } a, b;
    a.f = x;
    b.i = __builtin_amdgcn_update_dpp(0, a.i, CTRL, 0xF, 0xF, true);
    return x + b.f;
}
__device__ __forceinline__ float sum16(float t) {
    t = dpp_add<0xB1>(t);
    t = dpp_add<0x4E>(t);
    t = dpp_add<0x124>(t);
    t = dpp_add<0x128>(t);
    return t;
}

// hand-fused multi-value 16-lane butterflies (v_add_f32_dpp).
// VALU->DPP hazard needs 2 wait states: entry s_nop 1; interior spacing >=4.
#define _D(i, CTRL) "v_add_f32_dpp %" #i ", %" #i ", %" #i " " CTRL \
                    " row_mask:0xf bank_mask:0xf bound_ctrl:0\n\t"
#define _C1 "quad_perm:[1,0,3,2]"
#define _C2 "quad_perm:[2,3,0,1]"
#define _C3 "row_ror:4"
#define _C4 "row_ror:8"

__device__ __forceinline__ void sum16x6(float& a0, float& a1, float& a2,
                                        float& a3, float& a4, float& a5) {
    asm("s_nop 1\n\t"
        _D(0,_C1) _D(1,_C1) _D(2,_C1) _D(3,_C1) _D(4,_C1) _D(5,_C1)
        _D(0,_C2) _D(1,_C2) _D(2,_C2) _D(3,_C2) _D(4,_C2) _D(5,_C2)
        _D(0,_C3) _D(1,_C3) _D(2,_C3) _D(3,_C3) _D(4,_C3) _D(5,_C3)
        _D(0,_C4) _D(1,_C4) _D(2,_C4) _D(3,_C4) _D(4,_C4) _D(5,_C4)
        : "+v"(a0), "+v"(a1), "+v"(a2), "+v"(a3), "+v"(a4), "+v"(a5));
}

__device__ __forceinline__ void sum16x5(float& a0, float& a1, float& a2,
                                        float& a3, float& a4) {
    asm("s_nop 1\n\t"
        _D(0,_C1) _D(1,_C1) _D(2,_C1) _D(3,_C1) _D(4,_C1)
        _D(0,_C2) _D(1,_C2) _D(2,_C2) _D(3,_C2) _D(4,_C2)
        _D(0,_C3) _D(1,_C3) _D(2,_C3) _D(3,_C3) _D(4,_C3)
        _D(0,_C4) _D(1,_C4) _D(2,_C4) _D(3,_C4) _D(4,_C4)
        : "+v"(a0), "+v"(a1), "+v"(a2), "+v"(a3), "+v"(a4));
}

// Layout: wave w <-> template w; 64 lanes = 4 node-slots (p) x 16 lanes.
// Lane l owns row j=l+1; row 0 is register-replicated across the group.
// K=10 columns live in registers. TK arrays double as eK (inner loop) and
// Tp (outer boundary) -- never simultaneously live, saving 20 VGPRs.
__global__ __launch_bounds__(THREADS, 8) void ltfgw_kernel(
    const float* __restrict__ x,      // [N,128]
    const int*   __restrict__ ei,     // edge_index[0], [N*DEG]
    const float* __restrict__ tmpl,   // [T,K,K]
    const float* __restrict__ tf,     // [T,K,128]
    float* __restrict__ out,          // [N,T]
    int N)
{
    constexpr int SLAB = MM * PITCH;     // 2244 floats per node
    __shared__ float sFi[NPB * SLAB];    // 35904 B

    const int tid = threadIdx.x;
    const int b0  = blockIdx.x * NPB;

    // ---- stage Fi
    {
        const int kq = tid & 31;
        for (int r = tid >> 5; r < NPB * MM; r += (THREADS >> 5)) {
            int p = r / MM, j = r % MM;
            int node = b0 + p;
            if (node < N) {
                int src = (j == 0) ? node : ei[node * DEG + (j - 1)];
                float4 v4 = *(const float4*)(x + (size_t)src * DD + kq * 4);
                *(float4*)(&sFi[p * SLAB + j * PITCH + kq * 4]) = v4;
            }
        }
    }
    __syncthreads();

    const int w     = tid >> 6;
    const int wu    = __builtin_amdgcn_readfirstlane(w);
    const int lane  = tid & 63;
    const int p     = lane >> 4;
    const int l     = lane & 15;
    const int gbase = lane & ~15;
    const int node  = b0 + p;

    const int cl = (l < KT) ? l : 0;
    // Ct row base for column cl (8B-aligned: 40-byte row stride)
    const float* ctp = tmpl + ((size_t)wu * KT + cl) * KT;

    // ---- ct2q = (Ct^2 @ q)[cl]
    float ct2q;
    {
        v2f r0 = *(const v2f*)(ctp);
        v2f r1 = *(const v2f*)(ctp + 2);
        v2f r2 = *(const v2f*)(ctp + 4);
        v2f r3 = *(const v2f*)(ctp + 6);
        v2f r4 = *(const v2f*)(ctp + 8);
        v2f acc = pk_fma(r0, r0, (v2f){0.f, 0.f});
        acc = pk_fma(r1, r1, acc);
        acc = pk_fma(r2, r2, acc);
        acc = pk_fma(r3, r3, acc);
        acc = pk_fma(r4, r4, acc);
        ct2q = (acc.x + acc.y) * (1.f / KT);
    }

    // ---- M main pass: own row (LDS) vs 10 template rows (SGPR via s_load)
    const float* myrow = &sFi[p * SLAB + (l + 1) * PITCH];
    const float* tw    = tf + (size_t)wu * KT * DD;   // wave-uniform
    v2f dotv[KT];
#pragma unroll
    for (int c = 0; c < KT; ++c) dotv[c] = (v2f){0.f, 0.f};
    v2f nrmv = (v2f){0.f, 0.f};
#pragma unroll 4
    for (int kk = 0; kk < DD; kk += 4) {
        v4f a4 = *(const v4f*)(myrow + kk);
        nrmv = pk_fma(a4.lo, a4.lo, nrmv);
        nrmv = pk_fma(a4.hi, a4.hi, nrmv);
#pragma unroll
        for (int c = 0; c < KT; ++c) {
            v4f f4 = *(const v4f*)(tw + c * DD + kk);   // uniform -> s_load
            dotv[c] = pk_fma_s(a4.lo, f4.lo, dotv[c]);
            dotv[c] = pk_fma_s(a4.hi, f4.hi, dotv[c]);
        }
    }
    float nrm_own = nrmv.x + nrmv.y;

    // ---- mini-pass: row 0 dots + template norms + row0 norm (k-distributed)
    float dot0[KT], nft[KT], n0p;
    {
        const float* row0 = &sFi[p * SLAB + 8 * l];
        v4f z0 = *(const v4f*)(row0);
        v4f z1 = *(const v4f*)(row0 + 4);
        v2f nn = pk_fma(z0.lo, z0.lo, (v2f){0.f, 0.f});
        nn = pk_fma(z0.hi, z0.hi, nn);
        nn = pk_fma(z1.lo, z1.lo, nn);
        nn = pk_fma(z1.hi, z1.hi, nn);
        n0p = nn.x + nn.y;
#pragma unroll
        for (int c = 0; c < KT; ++c) {
            const float* tr = tw + c * DD + 8 * l;   // lane-varying -> vector load
            v4f t0_ = *(const v4f*)(tr);
            v4f t1_ = *(const v4f*)(tr + 4);
            v2f d = pk_fma(z0.lo, t0_.lo, (v2f){0.f, 0.f});
            d = pk_fma(z0.hi, t0_.hi, d);
            d = pk_fma(z1.lo, t1_.lo, d);
            d = pk_fma(z1.hi, t1_.hi, d);
            dot0[c] = d.x + d.y;
            v2f nf = pk_fma(t0_.lo, t0_.lo, (v2f){0.f, 0.f});
            nf = pk_fma(t0_.hi, t0_.hi, nf);
            nf = pk_fma(t1_.lo, t1_.lo, nf);
            nf = pk_fma(t1_.hi, t1_.hi, nf);
            nft[c] = nf.x + nf.y;
        }
        sum16x6(dot0[0], dot0[1], dot0[2], dot0[3], dot0[4], dot0[5]);
        sum16x5(dot0[6], dot0[7], dot0[8], dot0[9], n0p);
        sum16x5(nft[0], nft[1], nft[2], nft[3], nft[4]);
        sum16x5(nft[5], nft[6], nft[7], nft[8], nft[9]);
    }

    // ---- hoisted mirror factors eM = exp2(-log2e * Mc)
    float eM_own[KT], eM0[KT];
#pragma unroll
    for (int c = 0; c < KT; ++c) {
        float mc0 = (n0p + nft[c] - 2.f * dot0[c]) * (1.f / DD);
        eM0[c] = FEXP2(-NLOG2E * mc0);
        float mcw = (nrm_own + nft[c] - 2.f * (dotv[c].x + dotv[c].y)) * (1.f / DD);
        eM_own[c] = FEXP2(-NLOG2E * mcw);
    }

    // ---- proximal Sinkhorn. TKo/TK0 hold Tp at outer boundaries, eK inside.
    float TKo[KT], TK0[KT], vv[KT];
#pragma unroll
    for (int c = 0; c < KT; ++c) {
        TKo[c] = 1.f / (MM * KT);
        TK0[c] = 1.f / (MM * KT);
    }
    float u_own = 0.f, u0 = 0.f;

#pragma unroll 1
    for (int outer = 0; outer < 5; ++outer) {
        // s[c] = 16-lane sum of Tp over neighbor rows
        float s[KT];
#pragma unroll
        for (int c = 0; c < KT; ++c) s[c] = TKo[c];
        sum16x5(s[0], s[1], s[2], s[3], s[4]);
        sum16x5(s[5], s[6], s[7], s[8], s[9]);

        // Ct row reload (L1-resident, 5x8B) + distributed Cs/C0 on column cl
        v2f r0 = *(const v2f*)(ctp);
        v2f r1 = *(const v2f*)(ctp + 2);
        v2f r2 = *(const v2f*)(ctp + 4);
        v2f r3 = *(const v2f*)(ctp + 6);
        v2f r4 = *(const v2f*)(ctp + 8);
        float Cs, C0;
        {
            float a = r0.x * s[0],   b = r0.y * s[1];
            a = fmaf(r1.x, s[2], a); b = fmaf(r1.y, s[3], b);
            a = fmaf(r2.x, s[4], a); b = fmaf(r2.y, s[5], b);
            a = fmaf(r3.x, s[6], a); b = fmaf(r3.y, s[7], b);
            a = fmaf(r4.x, s[8], a); b = fmaf(r4.y, s[9], b);
            Cs = a + b;
            float q = r0.x * TK0[0],   d = r0.y * TK0[1];
            q = fmaf(r1.x, TK0[2], q); d = fmaf(r1.y, TK0[3], d);
            q = fmaf(r2.x, TK0[4], q); d = fmaf(r2.y, TK0[5], d);
            q = fmaf(r3.x, TK0[6], q); d = fmaf(r3.y, TK0[7], d);
            q = fmaf(r4.x, TK0[8], q); d = fmaf(r4.y, TK0[9], d);
            C0 = q + d;
        }
        float e0 = FEXP2(-TWO_LOG2E * ((16.f / 17.f) + ct2q - 2.f * Cs));
        float e1 = FEXP2(-TWO_LOG2E * ((1.f  / 17.f) + ct2q - 2.f * C0));

        // Tp -> eK in place
#pragma unroll
        for (int c = 0; c < KT; ++c) {
            float E1c = __shfl(e1, gbase + c, 64);
            TKo[c] = TKo[c] * (eM_own[c] * E1c);
            float E0c = __shfl(e0, gbase + c, 64);
            TK0[c] = TK0[c] * (eM0[c] * E0c);
            vv[c] = VV0;   // vv'' = vv/QP
        }

        // 10 Sinkhorn iterations in the vv''-scaled domain:
        //   u = RQP * rcp(sum_c eK*vv'');  vv'' = rcp(sum_rows eK*u)
#pragma unroll 1
        for (int it = 0; it < 10; ++it) {
            float ra = TKo[0] * vv[0], rb = TKo[1] * vv[1];
            float qa = TK0[0] * vv[0], qb = TK0[1] * vv[1];
#pragma unroll
            for (int c = 2; c < KT; c += 2) {
                ra = fmaf(TKo[c],     vv[c],     ra);
                rb = fmaf(TKo[c + 1], vv[c + 1], rb);
                qa = fmaf(TK0[c],     vv[c],     qa);
                qb = fmaf(TK0[c + 1], vv[c + 1], qb);
            }
            u_own = RQP * FRCP(ra + rb);
            u0    = RQP * FRCP(qa + qb);
            float t[KT];
#pragma unroll
            for (int c = 0; c < KT; ++c) t[c] = TKo[c] * u_own;
            sum16x5(t[0], t[1], t[2], t[3], t[4]);
            sum16x5(t[5], t[6], t[7], t[8], t[9]);
#pragma unroll
            for (int c = 0; c < KT; ++c)
                vv[c] = FRCP(fmaf(TK0[c], u0, t[c]));
        }

        // eK -> Tp in place: Tp = (pw*QP) * u * eK * vv''
        float puw = PWQP * u_own, pu0 = PWQP * u0;
#pragma unroll
        for (int c = 0; c < KT; ++c) {
            TKo[c] = (TKo[c] * vv[c]) * puw;
            TK0[c] = (TK0[c] * vv[c]) * pu0;
        }
    }

    // ---- final objective from converged Tp
    float obj;
    {
        float s[KT];
#pragma unroll
        for (int c = 0; c < KT; ++c) s[c] = TKo[c];
        sum16x5(s[0], s[1], s[2], s[3], s[4]);
        sum16x5(s[5], s[6], s[7], s[8], s[9]);
        v2f r0 = *(const v2f*)(ctp);
        v2f r1 = *(const v2f*)(ctp + 2);
        v2f r2 = *(const v2f*)(ctp + 4);
        v2f r3 = *(const v2f*)(ctp + 6);
        v2f r4 = *(const v2f*)(ctp + 8);
        float Cs, C0;
        {
            float a = r0.x * s[0],   b = r0.y * s[1];
            a = fmaf(r1.x, s[2], a); b = fmaf(r1.y, s[3], b);
            a = fmaf(r2.x, s[4], a); b = fmaf(r2.y, s[5], b);
            a = fmaf(r3.x, s[6], a); b = fmaf(r3.y, s[7], b);
            a = fmaf(r4.x, s[8], a); b = fmaf(r4.y, s[9], b);
            Cs = a + b;
            float q = r0.x * TK0[0],   d = r0.y * TK0[1];
            q = fmaf(r1.x, TK0[2], q); d = fmaf(r1.y, TK0[3], d);
            q = fmaf(r2.x, TK0[4], q); d = fmaf(r2.y, TK0[5], d);
            q = fmaf(r3.x, TK0[6], q); d = fmaf(r3.y, TK0[7], d);
            q = fmaf(r4.x, TK0[8], q); d = fmaf(r4.y, TK0[9], d);
            C0 = q + d;
        }
        float g0l = (16.f / 17.f) + ct2q - 2.f * Cs;
        float g1l = (1.f  / 17.f) + ct2q - 2.f * C0;
        float obj_own = 0.f, obj0 = 0.f;
#pragma unroll
        for (int c = 0; c < KT; ++c) {
            float G1c = __shfl(g1l, gbase + c, 64);
            float hM  = -EPSLN2 * FLOG2(eM_own[c]);    // == 0.5*Mc_own[c]
            obj_own += TKo[c] * (hM + 0.5f * G1c);
            float G0c = __shfl(g0l, gbase + c, 64);
            float hM0 = -EPSLN2 * FLOG2(eM0[c]);       // == 0.5*Mc0[c]
            obj0 += TK0[c] * (hM0 + 0.5f * G0c);
        }
        obj = sum16(obj_own) + obj0;
    }

    if (l == 0 && node < N) out[node * TT + w] = obj;
}

extern "C" void kernel_launch(void* const* d_in, const int* in_sizes, int n_in,
                              void* d_out, int out_size, void* d_ws, size_t ws_size,
                              hipStream_t stream) {
    const float* x    = (const float*)d_in[0];
    const int*   ei   = (const int*)d_in[1];
    const float* tmpl = (const float*)d_in[2];
    const float* tf   = (const float*)d_in[3];
    float* out = (float*)d_out;
    int N = in_sizes[0] / DD;
    int grid = (N + NPB - 1) / NPB;
    hipLaunchKernelGGL(ltfgw_kernel, dim3(grid), dim3(THREADS), 0, stream,
                       x, ei, tmpl, tf, out, N);
}